// Round 4
// baseline (88.539 us; speedup 1.0000x reference)
//
#include <hip/hip_runtime.h>

// Problem constants (match reference)
#define BB 2
#define NN 131072
#define MM 512
#define GG 20
#define VV (GG * GG * GG)      // 8000
#define NBLKX 128              // K1 blocks per batch (256 thr, 4 pts/thr)
#define NBLK2 64               // K2 blocks per batch (512 thr, 4 pts/thr)

// Workspace layout:
//   0      partialMin : B*NBLKX*3 floats (3072 B) -- written K1 (no init needed)
//   4080   doneCtr    : 1 int (16 B slot)         -- zeroed in K1
//   4096   sums       : B*V*10 floats (640000 B)  -- zeroed in K1
#define OFF_PARTIAL 0
#define OFF_CTR     4080
#define OFF_SUMS    4096
#define ZI4         ((16 + 640000) / 16)   // 40001 int4 zero-stores (ctr+sums)

__device__ __forceinline__ int vox_coord(float p, float mn) {
    int i = (int)floorf((p - mn) * 2.0f);   // *2 == /0.5 (exact pow2 scale)
    return min(max(i, 0), GG - 1);
}

// ---- K1: distributed zero of ctr+sums + per-block coordinate-min partials
__global__ __launch_bounds__(256) void vox_min(const float* __restrict__ x,
                                               char* __restrict__ ws) {
    const int b = blockIdx.y;
    const int tid = blockIdx.x * 256 + threadIdx.x;                 // per batch
    const int gtid = (b * NBLKX + blockIdx.x) * 256 + threadIdx.x;  // global

    // zero counter + sums (read only by K2; kernel boundary orders it)
    {
        int4* z = (int4*)(ws + OFF_CTR);
        if (gtid < ZI4) z[gtid] = make_int4(0, 0, 0, 0);
    }

    // one group of 3 float4 (= 4 points) per thread
    const float4* xb = (const float4*)(x + (size_t)b * NN * 3);
    float4 f0 = xb[3 * tid + 0];
    float4 f1 = xb[3 * tid + 1];
    float4 f2 = xb[3 * tid + 2];
    float mx = fminf(fminf(f0.x, f0.w), fminf(f1.z, f2.y));
    float my = fminf(fminf(f0.y, f1.x), fminf(f1.w, f2.z));
    float mz = fminf(fminf(f0.z, f1.y), fminf(f2.x, f2.w));

    for (int off = 32; off > 0; off >>= 1) {
        mx = fminf(mx, __shfl_down(mx, off, 64));
        my = fminf(my, __shfl_down(my, off, 64));
        mz = fminf(mz, __shfl_down(mz, off, 64));
    }
    __shared__ float lmin[4][3];
    int wave = threadIdx.x >> 6;
    if ((threadIdx.x & 63) == 0) {
        lmin[wave][0] = mx; lmin[wave][1] = my; lmin[wave][2] = mz;
    }
    __syncthreads();
    if (threadIdx.x == 0) {
        float* pm = (float*)(ws + OFF_PARTIAL) + (b * NBLKX + blockIdx.x) * 3;
        pm[0] = fminf(fminf(lmin[0][0], lmin[1][0]), fminf(lmin[2][0], lmin[3][0]));
        pm[1] = fminf(fminf(lmin[0][1], lmin[1][1]), fminf(lmin[2][1], lmin[3][1]));
        pm[2] = fminf(fminf(lmin[0][2], lmin[1][2]), fminf(lmin[2][2], lmin[3][2]));
    }
}

// ---- K2: redundant {min fold (both batches) + sampled-voxel LDS bitmap},
//          accumulate sums for sampled voxels (HW f32 atomics), then the
//          LAST block (done-counter) finalizes all B*M outputs. -----------
// sums per (b,voxel): [cnt, sx, sy, sz, sxx, sxy, sxz, syy, syz, szz]
__global__ __launch_bounds__(512) void vox_accum(const float* __restrict__ x,
                                                 const int* __restrict__ sidx,
                                                 char* __restrict__ ws,
                                                 float* __restrict__ out) {
    const int b = blockIdx.y;
    const int t = threadIdx.x;
    const int tid = blockIdx.x * 512 + t;     // 0..32767 per batch (4 pts each)

    __shared__ float smin[BB][3];             // mins for BOTH batches
    __shared__ unsigned int bm[250];          // 8000-bit sampled-voxel bitmap
    __shared__ int lastFlag;

    if (t < 250) bm[t] = 0u;
    if (t < 384) {                            // 6 (batch,axis) pairs x 64 lanes
        const int pair = t >> 6, lane = t & 63;
        const int pb = pair / 3, axis = pair % 3;
        const float* pm = (const float*)(ws + OFF_PARTIAL);
        float m = fminf(pm[(pb * NBLKX + lane) * 3 + axis],
                        pm[(pb * NBLKX + lane + 64) * 3 + axis]);
        for (int off = 32; off > 0; off >>= 1)
            m = fminf(m, __shfl_down(m, off, 64));
        if (lane == 0) smin[pb][axis] = m;
    }
    __syncthreads();
    const float mnx = smin[b][0], mny = smin[b][1], mnz = smin[b][2];

    // build this batch's bitmap: 1 sample per thread (M=512), L2-hot gathers
    {
        const int pi = sidx[b * MM + t];
        const float* p = x + ((size_t)b * NN + pi) * 3;
        int ix = vox_coord(p[0], mnx);
        int iy = vox_coord(p[1], mny);
        int iz = vox_coord(p[2], mnz);
        int flat = (ix * GG + iy) * GG + iz;
        atomicOr(&bm[flat >> 5], 1u << (flat & 31));
    }
    __syncthreads();

    float* sums = (float*)(ws + OFF_SUMS) + (size_t)b * VV * 10;
    const float4* xb = (const float4*)(x + (size_t)b * NN * 3);
    float4 f0 = xb[3 * tid + 0];
    float4 f1 = xb[3 * tid + 1];
    float4 f2 = xb[3 * tid + 2];
    float px[4] = {f0.x, f0.w, f1.z, f2.y};
    float py[4] = {f0.y, f1.x, f1.w, f2.z};
    float pz[4] = {f0.z, f1.y, f2.x, f2.w};
#pragma unroll
    for (int k = 0; k < 4; ++k) {
        int ix = vox_coord(px[k], mnx);
        int iy = vox_coord(py[k], mny);
        int iz = vox_coord(pz[k], mnz);
        int flat = (ix * GG + iy) * GG + iz;
        if ((bm[flat >> 5] >> (flat & 31)) & 1u) {
            float* s = sums + (size_t)flat * 10;
            unsafeAtomicAdd(s + 0, 1.0f);
            unsafeAtomicAdd(s + 1, px[k]);
            unsafeAtomicAdd(s + 2, py[k]);
            unsafeAtomicAdd(s + 3, pz[k]);
            unsafeAtomicAdd(s + 4, px[k] * px[k]);
            unsafeAtomicAdd(s + 5, px[k] * py[k]);
            unsafeAtomicAdd(s + 6, px[k] * pz[k]);
            unsafeAtomicAdd(s + 7, py[k] * py[k]);
            unsafeAtomicAdd(s + 8, py[k] * pz[k]);
            unsafeAtomicAdd(s + 9, pz[k] * pz[k]);
        }
    }

    // ---- done-counter: last finishing block finalizes all outputs ----
    __threadfence();   // release: drain my atomics, make them device-visible
    if (t == 0)
        lastFlag = (atomicAdd((int*)(ws + OFF_CTR), 1) == NBLK2 * BB - 1);
    __syncthreads();
    if (!lastFlag) return;

    __threadfence();   // acquire: invalidate caches; see all blocks' atomics
#pragma unroll
    for (int k = 0; k < 2; ++k) {
        const int j = t + k * 512;            // 0..1023 == B*M outputs
        const int fb = j >> 9;
        const int pi = sidx[fb * MM + (j & (MM - 1))];
        const float* p = x + ((size_t)fb * NN + pi) * 3;
        int ix = vox_coord(p[0], smin[fb][0]);
        int iy = vox_coord(p[1], smin[fb][1]);
        int iz = vox_coord(p[2], smin[fb][2]);
        int flat = (ix * GG + iy) * GG + iz;
        const float* s = (const float*)(ws + OFF_SUMS) + ((size_t)fb * VV + flat) * 10;
        float cnt = s[0];
        float inv = 1.0f / fmaxf(cnt, 1.0f);
        float mx = s[1] * inv, my = s[2] * inv, mz = s[3] * inv;
        float cxx = s[4] * inv - mx * mx;
        float cxy = s[5] * inv - mx * my;
        float cxz = s[6] * inv - mx * mz;
        float cyy = s[7] * inv - my * my;
        float cyz = s[8] * inv - my * mz;
        float czz = s[9] * inv - mz * mz;
        float* o = out + (size_t)j * 12;
        o[0] = mx;  o[1] = my;  o[2] = mz;
        o[3] = cxx; o[4] = cxy; o[5] = cxz;
        o[6] = cxy; o[7] = cyy; o[8] = cyz;
        o[9] = cxz; o[10] = cyz; o[11] = czz;
    }
}

extern "C" void kernel_launch(void* const* d_in, const int* in_sizes, int n_in,
                              void* d_out, int out_size, void* d_ws, size_t ws_size,
                              hipStream_t stream) {
    const float* x = (const float*)d_in[0];   // (B, N, 3) fp32
    const int* sidx = (const int*)d_in[1];    // (B, M) int32
    float* out = (float*)d_out;               // (B, M, 12) fp32
    char* ws = (char*)d_ws;

    vox_min<<<dim3(NBLKX, BB), 256, 0, stream>>>(x, ws);
    vox_accum<<<dim3(NBLK2, BB), 512, 0, stream>>>(x, sidx, ws, out);
}

// Round 5
// 77.367 us; speedup vs baseline: 1.1444x; 1.1444x over previous
//
#include <hip/hip_runtime.h>

// Problem constants (match reference)
#define BB 2
#define NN 131072
#define MM 512
#define GG 20
#define VV (GG * GG * GG)      // 8000
#define NBLKX 128              // blocks per batch for min/accum

// Workspace layout:
//   0      partialMin : B*NBLKX*3 floats (3072 B) -- written K1 (no init needed)
//   4096   sums       : B*V*10 floats (640000 B)  -- zeroed distributed in K1
#define OFF_PARTIAL 0
#define OFF_SUMS    4096
#define ZI4         (640000 / 16)    // 40000 int4 zero-stores across 65536 threads

__device__ __forceinline__ int vox_coord(float p, float mn) {
    int i = (int)floorf((p - mn) * 2.0f);   // *2 == /0.5 (exact pow2 scale)
    return min(max(i, 0), GG - 1);
}

// Redundant per-block fold of the 128 per-block partial mins for batch b.
// Threads 0..191 participate (axis = t>>6, 64 lanes fold 2 partials each).
__device__ __forceinline__ void reduce_min_prologue(const char* ws, int b, int t,
                                                    float* smin) {
    if (t < 192) {
        const int axis = t >> 6, lane = t & 63;
        const float* pm = (const float*)(ws + OFF_PARTIAL);
        float m = fminf(pm[(b * NBLKX + lane) * 3 + axis],
                        pm[(b * NBLKX + lane + 64) * 3 + axis]);
        for (int off = 32; off > 0; off >>= 1)
            m = fminf(m, __shfl_down(m, off, 64));
        if (lane == 0) smin[axis] = m;
    }
}

// ---- K1: distributed zero of sums + per-block coordinate-min partials ----
__global__ __launch_bounds__(256) void vox_min(const float* __restrict__ x,
                                               char* __restrict__ ws) {
    const int b = blockIdx.y;
    const int tid = blockIdx.x * 256 + threadIdx.x;                 // per batch
    const int gtid = (b * NBLKX + blockIdx.x) * 256 + threadIdx.x;  // global

    // zero sums (16B stores; read only by later kernels; no ordering hazard)
    {
        int4* z = (int4*)(ws + OFF_SUMS);
        if (gtid < ZI4) z[gtid] = make_int4(0, 0, 0, 0);
    }

    // one group of 3 float4 (= 4 points) per thread
    const float4* xb = (const float4*)(x + (size_t)b * NN * 3);
    float4 f0 = xb[3 * tid + 0];
    float4 f1 = xb[3 * tid + 1];
    float4 f2 = xb[3 * tid + 2];
    float mx = fminf(fminf(f0.x, f0.w), fminf(f1.z, f2.y));
    float my = fminf(fminf(f0.y, f1.x), fminf(f1.w, f2.z));
    float mz = fminf(fminf(f0.z, f1.y), fminf(f2.x, f2.w));

    for (int off = 32; off > 0; off >>= 1) {
        mx = fminf(mx, __shfl_down(mx, off, 64));
        my = fminf(my, __shfl_down(my, off, 64));
        mz = fminf(mz, __shfl_down(mz, off, 64));
    }
    __shared__ float lmin[4][3];
    int wave = threadIdx.x >> 6;
    if ((threadIdx.x & 63) == 0) {
        lmin[wave][0] = mx; lmin[wave][1] = my; lmin[wave][2] = mz;
    }
    __syncthreads();
    if (threadIdx.x == 0) {
        float* pm = (float*)(ws + OFF_PARTIAL) + (b * NBLKX + blockIdx.x) * 3;
        pm[0] = fminf(fminf(lmin[0][0], lmin[1][0]), fminf(lmin[2][0], lmin[3][0]));
        pm[1] = fminf(fminf(lmin[0][1], lmin[1][1]), fminf(lmin[2][1], lmin[3][1]));
        pm[2] = fminf(fminf(lmin[0][2], lmin[1][2]), fminf(lmin[2][2], lmin[3][2]));
    }
}

// ---- K2: per-block redundant {min fold + sampled-voxel LDS bitmap}, then
//          accumulate sums for sampled voxels only (~330K HW atomics) ------
// sums per (b,voxel): [cnt, sx, sy, sz, sxx, sxy, sxz, syy, syz, szz]
__global__ __launch_bounds__(256) void vox_accum(const float* __restrict__ x,
                                                 const int* __restrict__ sidx,
                                                 char* __restrict__ ws) {
    const int b = blockIdx.y;
    const int t = threadIdx.x;
    const int tid = blockIdx.x * 256 + t;

    __shared__ float smin[3];
    __shared__ unsigned int bm[250];          // 8000-bit sampled-voxel bitmap

    if (t < 250) bm[t] = 0u;
    reduce_min_prologue(ws, b, t, smin);
    __syncthreads();
    const float mnx = smin[0], mny = smin[1], mnz = smin[2];

    // build bitmap: 2 samples per thread (M=512), scattered gathers (L2-hot)
#pragma unroll
    for (int k = 0; k < 2; ++k) {
        const int j = t + k * 256;
        const int pi = sidx[b * MM + j];
        const float* p = x + ((size_t)b * NN + pi) * 3;
        int ix = vox_coord(p[0], mnx);
        int iy = vox_coord(p[1], mny);
        int iz = vox_coord(p[2], mnz);
        int flat = (ix * GG + iy) * GG + iz;
        atomicOr(&bm[flat >> 5], 1u << (flat & 31));
    }
    __syncthreads();

    float* sums = (float*)(ws + OFF_SUMS) + (size_t)b * VV * 10;
    const float4* xb = (const float4*)(x + (size_t)b * NN * 3);
    float4 f0 = xb[3 * tid + 0];
    float4 f1 = xb[3 * tid + 1];
    float4 f2 = xb[3 * tid + 2];
    float px[4] = {f0.x, f0.w, f1.z, f2.y};
    float py[4] = {f0.y, f1.x, f1.w, f2.z};
    float pz[4] = {f0.z, f1.y, f2.x, f2.w};
#pragma unroll
    for (int k = 0; k < 4; ++k) {
        int ix = vox_coord(px[k], mnx);
        int iy = vox_coord(py[k], mny);
        int iz = vox_coord(pz[k], mnz);
        int flat = (ix * GG + iy) * GG + iz;
        if ((bm[flat >> 5] >> (flat & 31)) & 1u) {
            float* s = sums + (size_t)flat * 10;
            unsafeAtomicAdd(s + 0, 1.0f);
            unsafeAtomicAdd(s + 1, px[k]);
            unsafeAtomicAdd(s + 2, py[k]);
            unsafeAtomicAdd(s + 3, pz[k]);
            unsafeAtomicAdd(s + 4, px[k] * px[k]);
            unsafeAtomicAdd(s + 5, px[k] * py[k]);
            unsafeAtomicAdd(s + 6, px[k] * pz[k]);
            unsafeAtomicAdd(s + 7, py[k] * py[k]);
            unsafeAtomicAdd(s + 8, py[k] * pz[k]);
            unsafeAtomicAdd(s + 9, pz[k] * pz[k]);
        }
    }
}

// ---- K3: finalize mean/cov at sampled voxels (recomputes voxel ids) -----
__global__ __launch_bounds__(512) void vox_final(const float* __restrict__ x,
                                                 const int* __restrict__ sidx,
                                                 const char* __restrict__ ws,
                                                 float* __restrict__ out) {
    const int b = blockIdx.x;                 // one block per batch
    const int t = threadIdx.x;                // 0..511 == M samples

    __shared__ float smin[3];
    reduce_min_prologue(ws, b, t, smin);
    __syncthreads();

    const int pi = sidx[b * MM + t];
    const float* p = x + ((size_t)b * NN + pi) * 3;
    int ix = vox_coord(p[0], smin[0]);
    int iy = vox_coord(p[1], smin[1]);
    int iz = vox_coord(p[2], smin[2]);
    int flat = (ix * GG + iy) * GG + iz;

    const float* s = (const float*)(ws + OFF_SUMS) + ((size_t)b * VV + flat) * 10;
    float cnt = s[0];
    float inv = 1.0f / fmaxf(cnt, 1.0f);
    float mx = s[1] * inv, my = s[2] * inv, mz = s[3] * inv;
    float cxx = s[4] * inv - mx * mx;
    float cxy = s[5] * inv - mx * my;
    float cxz = s[6] * inv - mx * mz;
    float cyy = s[7] * inv - my * my;
    float cyz = s[8] * inv - my * mz;
    float czz = s[9] * inv - mz * mz;
    float* o = out + (size_t)(b * MM + t) * 12;
    o[0] = mx;  o[1] = my;  o[2] = mz;
    o[3] = cxx; o[4] = cxy; o[5] = cxz;
    o[6] = cxy; o[7] = cyy; o[8] = cyz;
    o[9] = cxz; o[10] = cyz; o[11] = czz;
}

extern "C" void kernel_launch(void* const* d_in, const int* in_sizes, int n_in,
                              void* d_out, int out_size, void* d_ws, size_t ws_size,
                              hipStream_t stream) {
    const float* x = (const float*)d_in[0];   // (B, N, 3) fp32
    const int* sidx = (const int*)d_in[1];    // (B, M) int32
    float* out = (float*)d_out;               // (B, M, 12) fp32
    char* ws = (char*)d_ws;

    vox_min<<<dim3(NBLKX, BB), 256, 0, stream>>>(x, ws);
    vox_accum<<<dim3(NBLKX, BB), 256, 0, stream>>>(x, sidx, ws);
    vox_final<<<BB, 512, 0, stream>>>(x, sidx, ws, out);
}